// Round 9
// baseline (75.130 us; speedup 1.0000x reference)
//
#include <hip/hip_runtime.h>

#define CF 2048
#define TT 64
#define TP 65
#define KK 16
#define SS 4
#define EE 64
#define BB 2
#define DT_CONST 0.005f

// ws: gram partials [64 blocks][136]

// ---------------- kernel A: windowed Gram, LDS-resident (no big per-thread arrays) ----
// grid 64; block 256. Stage 64 rows in LDS; A[lag]/S1[d] per row; 136 pair-threads
// assemble with <=7-term head/tail corrections. Per-thread regs ~10 floats.
__global__ void __launch_bounds__(256, 2) kA_gram(const float* __restrict__ events,
                                                  float* __restrict__ ws) {
    __shared__ float xs[64][65];     // +1 pad
    __shared__ float AL[64][16];
    __shared__ float S1L[64][16];
    const int tid = threadIdx.x;

    // coalesced load of the block's contiguous 64-row span (4096 floats)
    const float4* src = reinterpret_cast<const float4*>(events + (size_t)blockIdx.x * 4096);
#pragma unroll
    for (int k = 0; k < 4; ++k) {
        int j = tid + k * 256;                   // [0,1024)
        float4 v = src[j];
        int r = j >> 4, c0 = (j & 15) << 2;
        xs[r][c0] = v.x; xs[r][c0+1] = v.y; xs[r][c0+2] = v.z; xs[r][c0+3] = v.w;
    }
    __syncthreads();

    // A[r][lag] = sum_{u=0}^{63-lag} x[u]x[u+lag];  S1[r][d] = sum_{u=max(0,d-8)}^{min(63,d+56)} x[u]
#pragma unroll
    for (int k = 0; k < 4; ++k) {
        int v = tid + k * 256;                   // [0,1024)
        int r = v >> 4, lag = v & 15;
        float a = 0.f;
        for (int u = 0; u < 64 - lag; ++u) a += xs[r][u] * xs[r][u + lag];
        AL[r][lag] = a;
        const int d = lag;
        const int lo = (d - 8 > 0) ? d - 8 : 0;
        const int hi = (d + 56 < 63) ? d + 56 : 63;
        float s = 0.f;
        for (int u = lo; u <= hi; ++u) s += xs[r][u];
        S1L[r][d] = s;
    }
    __syncthreads();

    // pair assembly: G(d1,d2) = sum_r [ A[lag] - head - tail - S1[d1]S1[d2]/65 ]
    if (tid < 136) {
        int pp = tid, d1 = 0;
        while (pp >= KK - d1) { pp -= KK - d1; ++d1; }
        const int d2 = d1 + pp;
        const int lag = d2 - d1;
        float g = 0.f;
        for (int r = 0; r < 64; ++r) {
            float gr = AL[r][lag] - S1L[r][d1] * S1L[r][d2] * (1.f / 65.f);
            for (int u = 0; u <= d1 - 9; ++u)          // head (d1>=9 only)
                gr -= xs[r][u] * xs[r][u + lag];
            for (int u = d1 + 57; u <= 63 - lag; ++u)  // tail (d2<=6 only)
                gr -= xs[r][u] * xs[r][u + lag];
            g += gr;
        }
        ws[blockIdx.x * 136 + tid] = g;
    }
}

// ---------------- kernel B2: redundant prologue (kM) + spill-free seg conv (R8 verbatim) ----
__global__ void __launch_bounds__(256, 4) kB2_main(
        const float* __restrict__ events, const float* __restrict__ tc,
        const float* __restrict__ tk, const float* __restrict__ w1,
        const float* __restrict__ b1, const float* __restrict__ w2,
        const float* __restrict__ b2, const float* __restrict__ ws,
        float* __restrict__ out) {
    __shared__ float buf[4672];           // prologue: Gf[512]|combL[4096]|fvL[8]; conv: 64*65=4160
    __shared__ float wkL[BB * EE * KK];   // 2048
    float* Gf    = buf;                   // [2][16][16]
    float* combL = buf + 512;             // [4][64][16]
    float* fvL   = buf + 4608;            // [2][4]
    const int tid = threadIdx.x;

    // --- Gram partial reduce -> full symmetric G per b ---
    for (int V = tid; V < BB * 136; V += 256) {
        int b = V / 136, p = V % 136;
        int pp = p, d1 = 0;
        while (pp >= KK - d1) { pp -= KK - d1; ++d1; }
        int d2 = d1 + pp;
        float acc = 0.f;
#pragma unroll
        for (int blk = 0; blk < 32; ++blk)
            acc += ws[(size_t)(b * 32 + blk) * 136 + p];
        Gf[(b * KK + d1) * KK + d2] = acc;
        Gf[(b * KK + d2) * KK + d1] = acc;
    }
    // --- combined kernels: thread = (s,e) ---
    {
        int s = tid >> 6;
        float inv = DT_CONST / tc[s];
        float dk[KK]; float dsum = 0.f;
#pragma unroll
        for (int j = 0; j < KK; ++j) { dk[j] = expf(-(float)j * inv); dsum += dk[j]; }
        float rn = 1.f / dsum;
#pragma unroll
        for (int i = 0; i < 4; ++i) {
            float4 v = reinterpret_cast<const float4*>(tk + tid * KK)[i];
            combL[tid * KK + 4*i + 0] = dk[4*i + 0] * rn * v.x;
            combL[tid * KK + 4*i + 1] = dk[4*i + 1] * rn * v.y;
            combL[tid * KK + 4*i + 2] = dk[4*i + 2] * rn * v.z;
            combL[tid * KK + 4*i + 3] = dk[4*i + 3] * rn * v.w;
        }
    }
    __syncthreads();
    // --- quadratic forms + e-reduction -> fv ---
    {
        float c[KK];
#pragma unroll
        for (int i = 0; i < 4; ++i) {
            float4 v = reinterpret_cast<const float4*>(combL + tid * KK)[i];
            c[4*i] = v.x; c[4*i+1] = v.y; c[4*i+2] = v.z; c[4*i+3] = v.w;
        }
        float acc0 = 0.f, acc1 = 0.f;
#pragma unroll
        for (int d1 = 0; d1 < KK; ++d1) {
            float cd1 = c[d1];
            float t0 = 0.5f * Gf[d1 * KK + d1] * cd1;
            float t1 = 0.5f * Gf[256 + d1 * KK + d1] * cd1;
#pragma unroll
            for (int d2 = d1 + 1; d2 < KK; ++d2) {
                t0 += Gf[d1 * KK + d2] * c[d2];
                t1 += Gf[256 + d1 * KK + d2] * c[d2];
            }
            acc0 += 2.f * cd1 * t0;
            acc1 += 2.f * cd1 * t1;
        }
#pragma unroll
        for (int sft = 1; sft < 64; sft <<= 1) {
            acc0 += __shfl_xor(acc0, sft, 64);
            acc1 += __shfl_xor(acc1, sft, 64);
        }
        if ((tid & 63) == 0) {
            const float scale = 1.f / 8388608.f;   // 1/(E*(Tp-1)*Cf)
            fvL[(tid >> 6)]     = acc0 * scale;
            fvL[4 + (tid >> 6)] = acc1 * scale;
        }
    }
    __syncthreads();
    // --- MLP + softmax + wk (into LDS) ---
    {
        int bt = tid >> 7;
        float fv[SS];
#pragma unroll
        for (int s = 0; s < SS; ++s) fv[s] = fvL[bt * SS + s];
        float h[8];
#pragma unroll
        for (int i = 0; i < 8; ++i) {
            float a = b1[i];
#pragma unroll
            for (int s = 0; s < SS; ++s) a += fv[s] * w1[i * SS + s];
            h[i] = a > 0.f ? a : 0.f;
        }
        float lg[SS]; float mx = -1e30f;
#pragma unroll
        for (int s = 0; s < SS; ++s) {
            float a = b2[s];
#pragma unroll
            for (int i = 0; i < 8; ++i) a += h[i] * w2[s * 8 + i];
            lg[s] = a; mx = fmaxf(mx, a);
        }
        float se = 0.f;
#pragma unroll
        for (int s = 0; s < SS; ++s) { lg[s] = expf(lg[s] - mx); se += lg[s]; }
        float attn[SS];
#pragma unroll
        for (int s = 0; s < SS; ++s) attn[s] = lg[s] / se;
#pragma unroll
        for (int k = 0; k < 8; ++k) {
            int o = tid * 8 + k;
            int e = (o >> 4) & 63, dt2 = o & 15;
            float a = 0.f;
#pragma unroll
            for (int s = 0; s < SS; ++s)
                a += attn[s] * combL[(s * EE + e) * KK + dt2];
            wkL[o] = a;
        }
    }
    __syncthreads();   // wk ready; buf free for conv staging

    // --- conv: 4 iterations of 64-row chunks (R4 seg scheme) ---
    const int seg = tid >> 6;                    // wave-uniform
    const int r   = tid & 63;
#pragma unroll 1
    for (int it = 0; it < 4; ++it) {
        const int c2 = blockIdx.x + (it << 10);  // chunk [0,4096)
        const int be = c2 >> 5;
        const int b  = be >> 6;
        const int rowg = (c2 << 6) + r;
        const float* xr = events + (((size_t)b << 11) + (rowg & (CF - 1))) * TT;

        float wk[KK];
#pragma unroll
        for (int i = 0; i < 4; ++i) {
            float4 v = reinterpret_cast<const float4*>(wkL + be * KK)[i];
            wk[4*i] = v.x; wk[4*i+1] = v.y; wk[4*i+2] = v.z; wk[4*i+3] = v.w;
        }

        float win[32];
        if (seg == 0) {                          // t 0..15, u -8..22
#pragma unroll
            for (int k = 0; k < 8; ++k) win[k] = 0.f;
#pragma unroll
            for (int k = 0; k < 6; ++k) {
                float4 v = reinterpret_cast<const float4*>(xr)[k];
                win[8+4*k] = v.x; win[9+4*k] = v.y; win[10+4*k] = v.z; win[11+4*k] = v.w;
            }
        } else if (seg == 3) {                   // t 48..64, u 40..71
#pragma unroll
            for (int k = 0; k < 6; ++k) {
                float4 v = reinterpret_cast<const float4*>(xr + 40)[k];
                win[4*k] = v.x; win[4*k+1] = v.y; win[4*k+2] = v.z; win[4*k+3] = v.w;
            }
#pragma unroll
            for (int k = 24; k < 32; ++k) win[k] = 0.f;
        } else {                                 // seg1: u 8..39, seg2: u 24..55
            const float* bp2 = xr + (seg == 1 ? 8 : 24);
#pragma unroll
            for (int k = 0; k < 8; ++k) {
                float4 v = reinterpret_cast<const float4*>(bp2)[k];
                win[4*k] = v.x; win[4*k+1] = v.y; win[4*k+2] = v.z; win[4*k+3] = v.w;
            }
        }

        float acc[16];
#pragma unroll
        for (int i = 0; i < 16; ++i) acc[i] = 0.f;
#pragma unroll
        for (int dt = 0; dt < 16; ++dt) {
            float w = wk[dt];
#pragma unroll
            for (int i = 0; i < 16; ++i) acc[i] += w * win[i + dt];
        }
        float acc16 = 0.f;
        if (seg == 3) {
#pragma unroll
            for (int dt = 0; dt < 8; ++dt) acc16 += wk[dt] * win[16 + dt];
        }

        __syncthreads();                         // buf free (prev copy-out / prologue done)
        float* bp = buf + r * TP + seg * 16;
#pragma unroll
        for (int i = 0; i < 16; ++i) bp[i] = acc[i];
        if (seg == 3) bp[16] = acc16;
        __syncthreads();

        const float4* bs = reinterpret_cast<const float4*>(buf);
        float4* od = reinterpret_cast<float4*>(out + (size_t)c2 * (64 * TP));
        for (int j = tid; j < 64 * TP / 4; j += 256)
            od[j] = bs[j];
    }
}

extern "C" void kernel_launch(void* const* d_in, const int* in_sizes, int n_in,
                              void* d_out, int out_size, void* d_ws, size_t ws_size,
                              hipStream_t stream) {
    const float* events = (const float*)d_in[0];
    const float* tc     = (const float*)d_in[1];
    const float* tk     = (const float*)d_in[2];
    const float* w1     = (const float*)d_in[3];
    const float* b1     = (const float*)d_in[4];
    const float* w2     = (const float*)d_in[5];
    const float* b2     = (const float*)d_in[6];
    float* out = (float*)d_out;
    float* ws  = (float*)d_ws;

    hipLaunchKernelGGL(kA_gram,  dim3(64),   dim3(256), 0, stream, events, ws);
    hipLaunchKernelGGL(kB2_main, dim3(1024), dim3(256), 0, stream,
                       events, tc, tk, w1, b1, w2, b2, ws, out);
}

// Round 10
// 40.868 us; speedup vs baseline: 1.8384x; 1.8384x over previous
//
#include <hip/hip_runtime.h>

#define CF 2048
#define TT 64
#define TP 65
#define KK 16
#define SS 4
#define EE 64
#define BB 2
#define DT_CONST 0.005f

// ws: gram partials [256 blocks][136]

// ---------------- kernel A: lag-major sliding-correlation Gram ----------------
// grid 256; block 256 = (16 rows) x (16 lags). All loop trip counts are
// compile-time (full unroll -> pipelined independent LDS reads).
// Thread (r, lag): C(d1) = sum_{t=0}^{64} xp[t+d1]*xp[t+d1+lag], computed
// incrementally: C(d1+1) = C(d1) - xp[d1]xp[d1+lag] + xp[65+d1]xp[65+d1+lag].
__global__ void __launch_bounds__(256, 2) kA_gram(const float* __restrict__ events,
                                                  float* __restrict__ ws) {
    __shared__ float xs[16][97];    // xpad rows: [0..7]=0, [8..71]=x, [72..96]=0
    __shared__ float S1L[16][16];
    __shared__ float part[16][136];
    const int tid = threadIdx.x;

    // stage 16 rows (4 KB contiguous), coalesced; zero the pads
    {
        const float4* src = reinterpret_cast<const float4*>(
            events + (size_t)blockIdx.x * (16 * TT));
        float4 v = src[tid];
        int r = tid >> 4, c0 = ((tid & 15) << 2) + 8;
        xs[r][c0] = v.x; xs[r][c0+1] = v.y; xs[r][c0+2] = v.z; xs[r][c0+3] = v.w;
        for (int idx = tid; idx < 16 * 33; idx += 256) {
            int rr = idx / 33, k = idx % 33;
            int c = (k < 8) ? k : (k + 64);
            xs[rr][c] = 0.f;
        }
    }
    __syncthreads();

    const int r   = tid >> 4;
    const int lag = tid & 15;

    // S1[r][d] = sum_{t=0}^{64} xpad[t+d]  (thread computes slot d = lag)
    {
        float s = 0.f;
#pragma unroll
        for (int u = 0; u <= 64; ++u) s += xs[r][lag + u];
        S1L[r][lag] = s;
    }
    __syncthreads();

    {
        const float inv65 = 1.f / 65.f;
        float C = 0.f;
#pragma unroll
        for (int u = 0; u <= 64; ++u) C += xs[r][u] * xs[r][u + lag];
        part[r][lag] = C - S1L[r][0] * S1L[r][lag] * inv65;   // pair (0, lag): p = lag
#pragma unroll
        for (int d1 = 1; d1 <= 15; ++d1) {
            C += xs[r][64 + d1] * xs[r][64 + d1 + lag]
               - xs[r][d1 - 1]  * xs[r][d1 - 1 + lag];
            if (lag + d1 <= 15) {
                int p = 16 * d1 - ((d1 * (d1 - 1)) >> 1) + lag;
                part[r][p] = C - S1L[r][d1] * S1L[r][d1 + lag] * inv65;
            }
        }
    }
    __syncthreads();

    if (tid < 136) {
        float g = 0.f;
#pragma unroll
        for (int rr = 0; rr < 16; ++rr) g += part[rr][tid];
        ws[blockIdx.x * 136 + tid] = g;
    }
}

// ---------------- kernel B2: redundant prologue + spill-free seg conv (R8, reduce=128) ----
__global__ void __launch_bounds__(256, 4) kB2_main(
        const float* __restrict__ events, const float* __restrict__ tc,
        const float* __restrict__ tk, const float* __restrict__ w1,
        const float* __restrict__ b1, const float* __restrict__ w2,
        const float* __restrict__ b2, const float* __restrict__ ws,
        float* __restrict__ out) {
    __shared__ float buf[4672];           // prologue: Gf[512]|combL[4096]|fvL[8]; conv: 64*65=4160
    __shared__ float wkL[BB * EE * KK];   // 2048
    float* Gf    = buf;                   // [2][16][16]
    float* combL = buf + 512;             // [4][64][16]
    float* fvL   = buf + 4608;            // [2][4]
    const int tid = threadIdx.x;

    // --- Gram partial reduce (128 sets per b) -> full symmetric G per b ---
    for (int V = tid; V < BB * 136; V += 256) {
        int b = V / 136, p = V % 136;
        int pp = p, d1 = 0;
        while (pp >= KK - d1) { pp -= KK - d1; ++d1; }
        int d2 = d1 + pp;
        float acc = 0.f;
#pragma unroll 32
        for (int blk = 0; blk < 128; ++blk)
            acc += ws[(size_t)(b * 128 + blk) * 136 + p];
        Gf[(b * KK + d1) * KK + d2] = acc;
        Gf[(b * KK + d2) * KK + d1] = acc;
    }
    // --- combined kernels: thread = (s,e) ---
    {
        int s = tid >> 6;
        float inv = DT_CONST / tc[s];
        float dk[KK]; float dsum = 0.f;
#pragma unroll
        for (int j = 0; j < KK; ++j) { dk[j] = expf(-(float)j * inv); dsum += dk[j]; }
        float rn = 1.f / dsum;
#pragma unroll
        for (int i = 0; i < 4; ++i) {
            float4 v = reinterpret_cast<const float4*>(tk + tid * KK)[i];
            combL[tid * KK + 4*i + 0] = dk[4*i + 0] * rn * v.x;
            combL[tid * KK + 4*i + 1] = dk[4*i + 1] * rn * v.y;
            combL[tid * KK + 4*i + 2] = dk[4*i + 2] * rn * v.z;
            combL[tid * KK + 4*i + 3] = dk[4*i + 3] * rn * v.w;
        }
    }
    __syncthreads();
    // --- quadratic forms + e-reduction -> fv ---
    {
        float c[KK];
#pragma unroll
        for (int i = 0; i < 4; ++i) {
            float4 v = reinterpret_cast<const float4*>(combL + tid * KK)[i];
            c[4*i] = v.x; c[4*i+1] = v.y; c[4*i+2] = v.z; c[4*i+3] = v.w;
        }
        float acc0 = 0.f, acc1 = 0.f;
#pragma unroll
        for (int d1 = 0; d1 < KK; ++d1) {
            float cd1 = c[d1];
            float t0 = 0.5f * Gf[d1 * KK + d1] * cd1;
            float t1 = 0.5f * Gf[256 + d1 * KK + d1] * cd1;
#pragma unroll
            for (int d2 = d1 + 1; d2 < KK; ++d2) {
                t0 += Gf[d1 * KK + d2] * c[d2];
                t1 += Gf[256 + d1 * KK + d2] * c[d2];
            }
            acc0 += 2.f * cd1 * t0;
            acc1 += 2.f * cd1 * t1;
        }
#pragma unroll
        for (int sft = 1; sft < 64; sft <<= 1) {
            acc0 += __shfl_xor(acc0, sft, 64);
            acc1 += __shfl_xor(acc1, sft, 64);
        }
        if ((tid & 63) == 0) {
            const float scale = 1.f / 8388608.f;   // 1/(E*(Tp-1)*Cf)
            fvL[(tid >> 6)]     = acc0 * scale;
            fvL[4 + (tid >> 6)] = acc1 * scale;
        }
    }
    __syncthreads();
    // --- MLP + softmax + wk (into LDS) ---
    {
        int bt = tid >> 7;
        float fv[SS];
#pragma unroll
        for (int s = 0; s < SS; ++s) fv[s] = fvL[bt * SS + s];
        float h[8];
#pragma unroll
        for (int i = 0; i < 8; ++i) {
            float a = b1[i];
#pragma unroll
            for (int s = 0; s < SS; ++s) a += fv[s] * w1[i * SS + s];
            h[i] = a > 0.f ? a : 0.f;
        }
        float lg[SS]; float mx = -1e30f;
#pragma unroll
        for (int s = 0; s < SS; ++s) {
            float a = b2[s];
#pragma unroll
            for (int i = 0; i < 8; ++i) a += h[i] * w2[s * 8 + i];
            lg[s] = a; mx = fmaxf(mx, a);
        }
        float se = 0.f;
#pragma unroll
        for (int s = 0; s < SS; ++s) { lg[s] = expf(lg[s] - mx); se += lg[s]; }
        float attn[SS];
#pragma unroll
        for (int s = 0; s < SS; ++s) attn[s] = lg[s] / se;
#pragma unroll
        for (int k = 0; k < 8; ++k) {
            int o = tid * 8 + k;
            int e = (o >> 4) & 63, dt2 = o & 15;
            float a = 0.f;
#pragma unroll
            for (int s = 0; s < SS; ++s)
                a += attn[s] * combL[(s * EE + e) * KK + dt2];
            wkL[o] = a;
        }
    }
    __syncthreads();   // wk ready; buf free for conv staging

    // --- conv: 4 iterations of 64-row chunks (R4 seg scheme) ---
    const int seg = tid >> 6;                    // wave-uniform
    const int r   = tid & 63;
#pragma unroll 1
    for (int it = 0; it < 4; ++it) {
        const int c2 = blockIdx.x + (it << 10);  // chunk [0,4096)
        const int be = c2 >> 5;
        const int b  = be >> 6;
        const int rowg = (c2 << 6) + r;
        const float* xr = events + (((size_t)b << 11) + (rowg & (CF - 1))) * TT;

        float wk[KK];
#pragma unroll
        for (int i = 0; i < 4; ++i) {
            float4 v = reinterpret_cast<const float4*>(wkL + be * KK)[i];
            wk[4*i] = v.x; wk[4*i+1] = v.y; wk[4*i+2] = v.z; wk[4*i+3] = v.w;
        }

        float win[32];
        if (seg == 0) {                          // t 0..15, u -8..22
#pragma unroll
            for (int k = 0; k < 8; ++k) win[k] = 0.f;
#pragma unroll
            for (int k = 0; k < 6; ++k) {
                float4 v = reinterpret_cast<const float4*>(xr)[k];
                win[8+4*k] = v.x; win[9+4*k] = v.y; win[10+4*k] = v.z; win[11+4*k] = v.w;
            }
        } else if (seg == 3) {                   // t 48..64, u 40..71
#pragma unroll
            for (int k = 0; k < 6; ++k) {
                float4 v = reinterpret_cast<const float4*>(xr + 40)[k];
                win[4*k] = v.x; win[4*k+1] = v.y; win[4*k+2] = v.z; win[4*k+3] = v.w;
            }
#pragma unroll
            for (int k = 24; k < 32; ++k) win[k] = 0.f;
        } else {                                 // seg1: u 8..39, seg2: u 24..55
            const float* bp2 = xr + (seg == 1 ? 8 : 24);
#pragma unroll
            for (int k = 0; k < 8; ++k) {
                float4 v = reinterpret_cast<const float4*>(bp2)[k];
                win[4*k] = v.x; win[4*k+1] = v.y; win[4*k+2] = v.z; win[4*k+3] = v.w;
            }
        }

        float acc[16];
#pragma unroll
        for (int i = 0; i < 16; ++i) acc[i] = 0.f;
#pragma unroll
        for (int dt = 0; dt < 16; ++dt) {
            float w = wk[dt];
#pragma unroll
            for (int i = 0; i < 16; ++i) acc[i] += w * win[i + dt];
        }
        float acc16 = 0.f;
        if (seg == 3) {
#pragma unroll
            for (int dt = 0; dt < 8; ++dt) acc16 += wk[dt] * win[16 + dt];
        }

        __syncthreads();                         // buf free (prev copy-out / prologue done)
        float* bp = buf + r * TP + seg * 16;
#pragma unroll
        for (int i = 0; i < 16; ++i) bp[i] = acc[i];
        if (seg == 3) bp[16] = acc16;
        __syncthreads();

        const float4* bs = reinterpret_cast<const float4*>(buf);
        float4* od = reinterpret_cast<float4*>(out + (size_t)c2 * (64 * TP));
        for (int j = tid; j < 64 * TP / 4; j += 256)
            od[j] = bs[j];
    }
}

extern "C" void kernel_launch(void* const* d_in, const int* in_sizes, int n_in,
                              void* d_out, int out_size, void* d_ws, size_t ws_size,
                              hipStream_t stream) {
    const float* events = (const float*)d_in[0];
    const float* tc     = (const float*)d_in[1];
    const float* tk     = (const float*)d_in[2];
    const float* w1     = (const float*)d_in[3];
    const float* b1     = (const float*)d_in[4];
    const float* w2     = (const float*)d_in[5];
    const float* b2     = (const float*)d_in[6];
    float* out = (float*)d_out;
    float* ws  = (float*)d_ws;

    hipLaunchKernelGGL(kA_gram,  dim3(256),  dim3(256), 0, stream, events, ws);
    hipLaunchKernelGGL(kB2_main, dim3(1024), dim3(256), 0, stream,
                       events, tc, tk, w1, b1, w2, b2, ws, out);
}

// Round 11
// 36.783 us; speedup vs baseline: 2.0425x; 1.1110x over previous
//
#include <hip/hip_runtime.h>

#define CF 2048
#define TT 64
#define TP 65
#define KK 16
#define SS 4
#define EE 64
#define BB 2
#define DT_CONST 0.005f

typedef float f32x4 __attribute__((ext_vector_type(4)));
typedef short bf16x8 __attribute__((ext_vector_type(8)));

// ws layout: transposed gram partials [272 slots][128 tiles]  (slot = b*136 + p)

// ---------------- kernel A: sliding-correlation Gram (R10 verbatim, transposed store) ----
// grid 256; block 256 = (16 rows) x (16 lags); all trip counts compile-time.
__global__ void __launch_bounds__(256, 2) kA_gram(const float* __restrict__ events,
                                                  float* __restrict__ ws) {
    __shared__ float xs[16][97];    // xpad rows: [0..7]=0, [8..71]=x, [72..96]=0
    __shared__ float S1L[16][16];
    __shared__ float part[16][136];
    const int tid = threadIdx.x;
    const int bq  = blockIdx.x >> 7;          // b

    {
        const float4* src = reinterpret_cast<const float4*>(
            events + (size_t)blockIdx.x * (16 * TT));
        float4 v = src[tid];
        int r = tid >> 4, c0 = ((tid & 15) << 2) + 8;
        xs[r][c0] = v.x; xs[r][c0+1] = v.y; xs[r][c0+2] = v.z; xs[r][c0+3] = v.w;
        for (int idx = tid; idx < 16 * 33; idx += 256) {
            int rr = idx / 33, k = idx % 33;
            int c = (k < 8) ? k : (k + 64);
            xs[rr][c] = 0.f;
        }
    }
    __syncthreads();

    const int r   = tid >> 4;
    const int lag = tid & 15;

    {
        float s = 0.f;
#pragma unroll
        for (int u = 0; u <= 64; ++u) s += xs[r][lag + u];
        S1L[r][lag] = s;
    }
    __syncthreads();

    {
        const float inv65 = 1.f / 65.f;
        float C = 0.f;
#pragma unroll
        for (int u = 0; u <= 64; ++u) C += xs[r][u] * xs[r][u + lag];
        part[r][lag] = C - S1L[r][0] * S1L[r][lag] * inv65;
#pragma unroll
        for (int d1 = 1; d1 <= 15; ++d1) {
            C += xs[r][64 + d1] * xs[r][64 + d1 + lag]
               - xs[r][d1 - 1]  * xs[r][d1 - 1 + lag];
            if (lag + d1 <= 15) {
                int p = 16 * d1 - ((d1 * (d1 - 1)) >> 1) + lag;
                part[r][p] = C - S1L[r][d1] * S1L[r][d1 + lag] * inv65;
            }
        }
    }
    __syncthreads();

    if (tid < 136) {
        float g = 0.f;
#pragma unroll
        for (int rr = 0; rr < 16; ++rr) g += part[rr][tid];
        ws[((size_t)(bq * 136 + tid)) * 128 + (blockIdx.x & 127)] = g;
    }
}

// ---------------- kernel B3: prologue + MFMA conv (write-bound) ----------------
// grid 512 = b(2) x 256 cf-tiles of 8 rows; block 256 = 4 waves (wave = e-tile).
__global__ void __launch_bounds__(256, 2) kB3_main(
        const float* __restrict__ events, const float* __restrict__ tc,
        const float* __restrict__ tk, const float* __restrict__ w1,
        const float* __restrict__ b1, const float* __restrict__ w2,
        const float* __restrict__ b2, const float* __restrict__ ws,
        float* __restrict__ out) {
    __shared__ float U[5248];                       // prologue Gf|combL|fvL ; conv stage [64][82]
    __shared__ float xs[8 * 97];                    // xpad rows (survive whole kernel)
    __shared__ __align__(16) unsigned short wkbh[64 * 32];   // wk hi, K-padded to 32 (zeros)
    __shared__ __align__(16) unsigned short wkbl[64 * 32];   // wk lo
    __shared__ __align__(16) unsigned short BmatTh[80 * 24 + 16];  // im2col^T hi [t][k]
    __shared__ __align__(16) unsigned short BmatTl[80 * 24 + 16];  // im2col^T lo
    float* Gf    = U;                               // [2][16][16]
    float* combL = U + 512;                         // [4][64][16]
    float* fvL   = U + 4608;                        // [2][4]
    const int tid = threadIdx.x;
    const int bid = blockIdx.x;
    const int b   = bid >> 8;

    // --- section 1: xs stage + Gram reduce (coalesced float4) + combined ---
    for (int idx = tid; idx < 8 * 33; idx += 256) {
        int rr = idx / 33, k = idx % 33;
        int c = (k < 8) ? k : (k + 64);
        xs[rr * 97 + c] = 0.f;
    }
    if (tid < 128) {
        float4 v = reinterpret_cast<const float4*>(events + (size_t)bid * 512)[tid];
        int rr = tid >> 4, c0 = ((tid & 15) << 2) + 8;
        xs[rr * 97 + c0] = v.x; xs[rr * 97 + c0 + 1] = v.y;
        xs[rr * 97 + c0 + 2] = v.z; xs[rr * 97 + c0 + 3] = v.w;
    }
    for (int v = tid; v < 272; v += 256) {
        int b2 = (v >= 136) ? 1 : 0;
        int p  = v - b2 * 136;
        int pp = p, d1 = 0;
        while (pp >= KK - d1) { pp -= KK - d1; ++d1; }
        int d2 = d1 + pp;
        const float4* rp = reinterpret_cast<const float4*>(ws + (size_t)v * 128);
        float acc = 0.f;
#pragma unroll
        for (int i = 0; i < 32; ++i) { float4 q = rp[i]; acc += (q.x + q.y) + (q.z + q.w); }
        Gf[(b2 * KK + d1) * KK + d2] = acc;
        Gf[(b2 * KK + d2) * KK + d1] = acc;
    }
    {
        int s = tid >> 6;
        float inv = DT_CONST / tc[s];
        float dk[KK]; float dsum = 0.f;
#pragma unroll
        for (int j = 0; j < KK; ++j) { dk[j] = expf(-(float)j * inv); dsum += dk[j]; }
        float rn = 1.f / dsum;
#pragma unroll
        for (int i = 0; i < 4; ++i) {
            float4 v = reinterpret_cast<const float4*>(tk + tid * KK)[i];
            combL[tid * KK + 4*i + 0] = dk[4*i + 0] * rn * v.x;
            combL[tid * KK + 4*i + 1] = dk[4*i + 1] * rn * v.y;
            combL[tid * KK + 4*i + 2] = dk[4*i + 2] * rn * v.z;
            combL[tid * KK + 4*i + 3] = dk[4*i + 3] * rn * v.w;
        }
    }
    __syncthreads();

    // --- section 2: quadratic forms -> fv ---
    {
        float c[KK];
#pragma unroll
        for (int i = 0; i < 4; ++i) {
            float4 v = reinterpret_cast<const float4*>(combL + tid * KK)[i];
            c[4*i] = v.x; c[4*i+1] = v.y; c[4*i+2] = v.z; c[4*i+3] = v.w;
        }
        float acc0 = 0.f, acc1 = 0.f;
#pragma unroll
        for (int d1 = 0; d1 < KK; ++d1) {
            float cd1 = c[d1];
            float t0 = 0.5f * Gf[d1 * KK + d1] * cd1;
            float t1 = 0.5f * Gf[256 + d1 * KK + d1] * cd1;
#pragma unroll
            for (int d2 = d1 + 1; d2 < KK; ++d2) {
                t0 += Gf[d1 * KK + d2] * c[d2];
                t1 += Gf[256 + d1 * KK + d2] * c[d2];
            }
            acc0 += 2.f * cd1 * t0;
            acc1 += 2.f * cd1 * t1;
        }
#pragma unroll
        for (int sft = 1; sft < 64; sft <<= 1) {
            acc0 += __shfl_xor(acc0, sft, 64);
            acc1 += __shfl_xor(acc1, sft, 64);
        }
        if ((tid & 63) == 0) {
            const float scale = 1.f / 8388608.f;    // 1/(E*(Tp-1)*Cf)
            fvL[(tid >> 6)]     = acc0 * scale;
            fvL[4 + (tid >> 6)] = acc1 * scale;
        }
    }
    __syncthreads();

    // --- section 3: MLP + softmax (own b) -> wk -> bf16 hi/lo, K-padded ---
    {
        float fv[SS];
#pragma unroll
        for (int s = 0; s < SS; ++s) fv[s] = fvL[b * SS + s];
        float h[8];
#pragma unroll
        for (int i = 0; i < 8; ++i) {
            float a = b1[i];
#pragma unroll
            for (int s = 0; s < SS; ++s) a += fv[s] * w1[i * SS + s];
            h[i] = a > 0.f ? a : 0.f;
        }
        float lg[SS]; float mx = -1e30f;
#pragma unroll
        for (int s = 0; s < SS; ++s) {
            float a = b2[s];
#pragma unroll
            for (int i = 0; i < 8; ++i) a += h[i] * w2[s * 8 + i];
            lg[s] = a; mx = fmaxf(mx, a);
        }
        float se = 0.f;
#pragma unroll
        for (int s = 0; s < SS; ++s) { lg[s] = expf(lg[s] - mx); se += lg[s]; }
        float attn[SS];
#pragma unroll
        for (int s = 0; s < SS; ++s) attn[s] = lg[s] / se;
#pragma unroll
        for (int j = 0; j < 4; ++j) {
            int idx = tid * 4 + j;                  // [0,1024)
            int e = idx >> 4, k2 = idx & 15;
            float a = 0.f;
#pragma unroll
            for (int s = 0; s < SS; ++s)
                a += attn[s] * combL[(s * EE + e) * KK + k2];
            unsigned int bits = __float_as_uint(a);
            unsigned short hh = (unsigned short)(bits >> 16);
            float hf = __uint_as_float(((unsigned int)hh) << 16);
            unsigned short ll = (unsigned short)(__float_as_uint(a - hf) >> 16);
            wkbh[e * 32 + k2] = hh;      wkbl[e * 32 + k2] = ll;
            wkbh[e * 32 + 16 + k2] = 0;  wkbl[e * 32 + 16 + k2] = 0;
        }
    }
    __syncthreads();

    // --- MFMA conv: per cf row, D[e][t] = sum_k wk[e][k] * xpad[t+k] ---
    const int w   = tid >> 6;       // wave = e-tile (m)
    const int l   = tid & 63;
    const int llo = l & 15, lhi = l >> 4;
    bf16x8 Ah = *reinterpret_cast<const bf16x8*>(&wkbh[(w * 16 + llo) * 32 + 8 * lhi]);
    bf16x8 Al = *reinterpret_cast<const bf16x8*>(&wkbl[(w * 16 + llo) * 32 + 8 * lhi]);
    float* stage = U;               // [64][82]
    const size_t obase0 = (size_t)b * 8519680 + (size_t)(bid & 255) * 520;

#pragma unroll 1
    for (int cf = 0; cf < 8; ++cf) {
        // build im2col^T (hi/lo): BmatT[t][k] = xpad[t+k], row stride 24 (16B-aligned)
        for (int idx = tid; idx < 1280; idx += 256) {
            int t = idx >> 4, k2 = idx & 15;
            float x = xs[cf * 97 + t + k2];
            unsigned int bits = __float_as_uint(x);
            unsigned short hh = (unsigned short)(bits >> 16);
            float hf = __uint_as_float(((unsigned int)hh) << 16);
            unsigned short ll = (unsigned short)(__float_as_uint(x - hf) >> 16);
            BmatTh[t * 24 + k2] = hh;
            BmatTl[t * 24 + k2] = ll;
        }
        __syncthreads();
#pragma unroll
        for (int nt = 0; nt < 5; ++nt) {
            bf16x8 Bh = *reinterpret_cast<const bf16x8*>(
                &BmatTh[(nt * 16 + llo) * 24 + 8 * lhi]);
            bf16x8 Bl = *reinterpret_cast<const bf16x8*>(
                &BmatTl[(nt * 16 + llo) * 24 + 8 * lhi]);
            f32x4 acc = {0.f, 0.f, 0.f, 0.f};
            acc = __builtin_amdgcn_mfma_f32_16x16x32_bf16(Al, Bh, acc, 0, 0, 0);
            acc = __builtin_amdgcn_mfma_f32_16x16x32_bf16(Ah, Bl, acc, 0, 0, 0);
            acc = __builtin_amdgcn_mfma_f32_16x16x32_bf16(Ah, Bh, acc, 0, 0, 0);
#pragma unroll
            for (int i = 0; i < 4; ++i)
                stage[(w * 16 + lhi * 4 + i) * 82 + nt * 16 + llo] = acc[i];
        }
        __syncthreads();
        // coalesced copy-out: per e, a 65-dword contiguous span
        {
            const size_t ob = obase0 + (size_t)cf * 65;
            int q = tid >> 6, t = tid & 63;
#pragma unroll
            for (int kk = 0; kk < 16; ++kk) {
                int e = q * 16 + kk;
                out[ob + (size_t)e * 133120 + t] = stage[e * 82 + t];
            }
            if (tid < 64) out[ob + (size_t)tid * 133120 + 64] = stage[tid * 82 + 64];
        }
        __syncthreads();
    }
}

extern "C" void kernel_launch(void* const* d_in, const int* in_sizes, int n_in,
                              void* d_out, int out_size, void* d_ws, size_t ws_size,
                              hipStream_t stream) {
    const float* events = (const float*)d_in[0];
    const float* tc     = (const float*)d_in[1];
    const float* tk     = (const float*)d_in[2];
    const float* w1     = (const float*)d_in[3];
    const float* b1     = (const float*)d_in[4];
    const float* w2     = (const float*)d_in[5];
    const float* b2     = (const float*)d_in[6];
    float* out = (float*)d_out;
    float* ws  = (float*)d_ws;

    hipLaunchKernelGGL(kA_gram,  dim3(256), dim3(256), 0, stream, events, ws);
    hipLaunchKernelGGL(kB3_main, dim3(512), dim3(256), 0, stream,
                       events, tc, tk, w1, b1, w2, b2, ws, out);
}